// Round 7
// baseline (218.175 us; speedup 1.0000x reference)
//
#include <hip/hip_runtime.h>
#include <stdint.h>

typedef __attribute__((ext_vector_type(8))) short short8;
typedef __attribute__((ext_vector_type(4))) float f32x4;
typedef __attribute__((ext_vector_type(16))) float f32x16;

#define BH 96
#define T 1024
#define D 256

static __device__ __forceinline__ unsigned short f2bf(float x){
  uint32_t u = __float_as_uint(x);
  uint32_t r = (u + 0x7FFFu + ((u >> 16) & 1u)) >> 16;  // RNE
  return (unsigned short)r;
}

static __device__ __forceinline__ uint32_t cvtpk_bf16(float lo, float hi){
  uint32_t r;
  asm("v_cvt_pk_bf16_f32 %0, %1, %2" : "=v"(r) : "v"(lo), "v"(hi));
  return r;
}

static __device__ __forceinline__ float exp2_fast(float x){
  float r;
  asm("v_exp_f32 %0, %1" : "=v"(r) : "v"(x));
  return r;
}

static __device__ __forceinline__ void gload_lds16(const void* g, void* l){
  __builtin_amdgcn_global_load_lds((const __attribute__((address_space(1))) void*)g,
                                   (__attribute__((address_space(3))) void*)l, 16, 0, 0);
}

// ---------------- Kernel 1: RoPE + (0.25*sqrt(log2e)) scale + bf16 cast
__global__ void k_rope(const float* __restrict__ Q, const float* __restrict__ freqs,
                       unsigned short* __restrict__ QR){
  const float SC = 0.25f * 1.20112241f;   // scores come out in log2 domain
  long idx = (long)blockIdx.x * 256 + threadIdx.x;
  long e = idx * 4;
  int n = (int)(e & (D - 1));
  int t = (int)((e >> 8) & (T - 1));
  float4 q = *(const float4*)(Q + e);
  float f0 = freqs[n];
  float f2 = freqs[n + 2];
  float ph0 = (float)t * f0; ph0 -= floorf(ph0);
  float ph2 = (float)t * f2; ph2 -= floorf(ph2);
  float c0 = __builtin_amdgcn_cosf(ph0), s0 = __builtin_amdgcn_sinf(ph0);
  float c2 = __builtin_amdgcn_cosf(ph2), s2 = __builtin_amdgcn_sinf(ph2);
  float o0 = (q.x * c0 - q.y * s0) * SC;
  float o1 = (q.y * c0 + q.x * s0) * SC;
  float o2 = (q.z * c2 - q.w * s2) * SC;
  float o3 = (q.w * c2 + q.z * s2) * SC;
  ushort4 o;
  o.x = f2bf(o0); o.y = f2bf(o1); o.z = f2bf(o2); o.w = f2bf(o3);
  *(ushort4*)(QR + e) = o;
}

// ---------------- Kernel 2: V [bh][t][n] fp32 -> Vt [bh][n][t] bf16
__global__ void k_transpose(const float* __restrict__ V, unsigned short* __restrict__ Vt){
  __shared__ unsigned short L[64 * 66];
  int bid = blockIdx.x;
  int head = bid >> 6;
  int rem = bid & 63;
  int t0 = (rem & 15) * 64;
  int n0 = (rem >> 4) * 64;
  int tid = threadIdx.x;
  const float* Vh = V + (long)head * T * D;
  unsigned short* Vth = Vt + (long)head * T * D;
  int lr = tid >> 4;
  int lc = (tid & 15) * 4;
#pragma unroll
  for (int i = 0; i < 4; ++i){
    int tl = i * 16 + lr;
    float4 v = *(const float4*)(Vh + (long)(t0 + tl) * D + n0 + lc);
    uint32_t w0 = (uint32_t)f2bf(v.x) | ((uint32_t)f2bf(v.y) << 16);
    uint32_t w1 = (uint32_t)f2bf(v.z) | ((uint32_t)f2bf(v.w) << 16);
    *(uint32_t*)&L[tl * 66 + lc]     = w0;
    *(uint32_t*)&L[tl * 66 + lc + 2] = w1;
  }
  __syncthreads();
  int nr = tid >> 3;
  int t8 = (tid & 7) * 8;
#pragma unroll
  for (int i = 0; i < 2; ++i){
    int n_row = i * 32 + nr;
    unsigned short u[8];
#pragma unroll
    for (int j = 0; j < 8; ++j) u[j] = L[(t8 + j) * 66 + n_row];
    uint4 o;
    o.x = (uint32_t)u[0] | ((uint32_t)u[1] << 16);
    o.y = (uint32_t)u[2] | ((uint32_t)u[3] << 16);
    o.z = (uint32_t)u[4] | ((uint32_t)u[5] << 16);
    o.w = (uint32_t)u[6] | ((uint32_t)u[7] << 16);
    *(uint4*)(Vth + (long)(n0 + n_row) * T + t0 + t8) = o;
  }
}

// ---------------- Kernel 3: flash attention, 32x32x16 MFMA everywhere.
// 4 waves x 32 q-rows (q-tile 128), KTILE=32, double-buffered LDS (64KB).
// Lane owns query q=lane&31 (C col); lane pair (l, l+32) splits the 32 keys.
// P redistribution: 8 cvt_pk + 8 shfl_xor(32) + 8 selects (unambiguous).
__global__ __launch_bounds__(256, 2) void k_flash(const unsigned short* __restrict__ QR,
                                                  const unsigned short* __restrict__ Vt,
                                                  float* __restrict__ Out){
  __shared__ short lds[2][16384];   // [buf][ K:0..8191 | V:8192..16383 ]
  int tid = threadIdx.x;
  int wid = tid >> 6, lane = tid & 63;
  int q31 = lane & 31, h = lane >> 5;

  int b = blockIdx.x;
  int xx = b & 7, sw = b >> 3;
  int qt = sw & 7, hg = sw >> 3;
  int head = hg * 8 + xx;           // XCD-bijective: one head's 8 q-blocks per XCD

  const unsigned short* qr = QR + (long)head * T * D;
  const unsigned short* vt = Vt + (long)head * T * D;
  int qb = qt * 128 + wid * 32;

  // staging source offsets (shorts): LDS slot i*8 holds, for K: chunk c=i>>6,
  // lane-slot s=i&63 -> K[s&31][(s>>5)*8 + c*16]; for V: g=i>>6 (=nb*2+kh) ->
  // Vt[(g>>1)*32 + (s&31)][(g&1)*16 + (s>>5)*8]  (row stride 1024)
  int bK[4], bV[4];
#pragma unroll
  for (int j = 0; j < 4; ++j){
    int i = tid + j * 256;
    int c = i >> 6, s = i & 63;
    bK[j] = (s & 31) * 256 + (s >> 5) * 8 + c * 16;
    bV[j] = ((c >> 1) * 32 + (s & 31)) * 1024 + (c & 1) * 16 + (s >> 5) * 8;
  }

  // Q fragments: lane holds Q[qb+q31][c*16 + h*8 + j]  (B-operand, col=q31)
  short8 qf[16];
#pragma unroll
  for (int c = 0; c < 16; ++c)
    qf[c] = *(const short8*)(qr + (long)(qb + q31) * D + c * 16 + h * 8);

  const f32x16 Zv = {0.f,0.f,0.f,0.f,0.f,0.f,0.f,0.f,0.f,0.f,0.f,0.f,0.f,0.f,0.f,0.f};
  f32x16 acc[8];
#pragma unroll
  for (int i = 0; i < 8; ++i) acc[i] = Zv;
  float m = -3e38f, lsum = 0.f;

  // prologue: stage tile 0 into buf 0
#pragma unroll
  for (int j = 0; j < 4; ++j){
    int i = tid + j * 256;
    gload_lds16(qr + bK[j], &lds[0][i * 8]);
    gload_lds16(vt + bV[j], &lds[0][8192 + i * 8]);
  }
  asm volatile("s_waitcnt vmcnt(0)" ::: "memory");
  __syncthreads();

  int buf = 0;
  for (int kb = 0; kb < T; kb += 32){
    if (kb + 32 < T){
      const unsigned short* sk = qr + (long)(kb + 32) * 256;
      const unsigned short* sv = vt + (kb + 32);
#pragma unroll
      for (int j = 0; j < 4; ++j){
        int i = tid + j * 256;
        gload_lds16(sk + bK[j], &lds[buf ^ 1][i * 8]);
        gload_lds16(sv + bV[j], &lds[buf ^ 1][8192 + i * 8]);
      }
    }
    const short* ldsK = &lds[buf][0];
    const short* ldsV = &lds[buf][8192];

    // QK^T: A=K(32 keys x 16k), B=Q(16k x 32 queries); two independent chains
    f32x16 sA = Zv, sB = Zv;
    __builtin_amdgcn_s_setprio(1);
#pragma unroll
    for (int c = 0; c < 8; ++c){
      short8 kf = *(const short8*)&ldsK[c * 512 + lane * 8];
      sA = __builtin_amdgcn_mfma_f32_32x32x16_bf16(kf, qf[c], sA, 0, 0, 0);
    }
#pragma unroll
    for (int c = 8; c < 16; ++c){
      short8 kf = *(const short8*)&ldsK[c * 512 + lane * 8];
      sB = __builtin_amdgcn_mfma_f32_32x32x16_bf16(kf, qf[c], sB, 0, 0, 0);
    }
    __builtin_amdgcn_s_setprio(0);
    f32x16 sc = sA + sB;   // scores: lane's query q31, key (r&3)+8*(r>>2)+4h

    // ---- softmax (log2 domain), defer-max, per-lane partials
    float lm = fmaxf(fmaxf(fmaxf(sc[0], sc[1]), fmaxf(sc[2], sc[3])),
                     fmaxf(fmaxf(sc[4], sc[5]), fmaxf(sc[6], sc[7])));
    lm = fmaxf(lm, fmaxf(fmaxf(fmaxf(sc[8], sc[9]), fmaxf(sc[10], sc[11])),
                         fmaxf(fmaxf(sc[12], sc[13]), fmaxf(sc[14], sc[15]))));
    lm = fmaxf(lm, __shfl_xor(lm, 32));   // lane pair shares the query
    if (__any(lm > m + 11.0f)){
      float mn = fmaxf(m, lm);
      float a = exp2_fast(m - mn);        // first tile: exp2(-inf)=0
      m = mn;
      lsum *= a;
#pragma unroll
      for (int nb = 0; nb < 8; ++nb) acc[nb] *= a;   // per-lane scalar (O^T form)
    }
    f32x16 p;
#pragma unroll
    for (int e = 0; e < 16; ++e) p[e] = exp2_fast(sc[e] - m);
    lsum += (((p[0]+p[1])+(p[2]+p[3])) + ((p[4]+p[5])+(p[6]+p[7])))
          + (((p[8]+p[9])+(p[10]+p[11])) + ((p[12]+p[13])+(p[14]+p[15])));

    // ---- P -> PV B-fragment (lane needs keys h*8+j per 16-key half-tile).
    // Own regs: h0 holds k0..3 (X0,X1), k8..11 (Y0,Y1); h1 holds k4..7, k12..15.
    uint32_t X0 = cvtpk_bf16(p[0],  p[1]);
    uint32_t X1 = cvtpk_bf16(p[2],  p[3]);
    uint32_t Y0 = cvtpk_bf16(p[4],  p[5]);
    uint32_t Y1 = cvtpk_bf16(p[6],  p[7]);
    uint32_t sX0 = __shfl_xor(X0, 32), sX1 = __shfl_xor(X1, 32);
    uint32_t sY0 = __shfl_xor(Y0, 32), sY1 = __shfl_xor(Y1, 32);
    uint4 f0;
    f0.x = h ? sY0 : X0;   // h0:(k0,k1)   h1:(k8,k9)
    f0.y = h ? sY1 : X1;   // h0:(k2,k3)   h1:(k10,k11)
    f0.z = h ? Y0  : sX0;  // h0:(k4,k5)   h1:(k12,k13)
    f0.w = h ? Y1  : sX1;  // h0:(k6,k7)   h1:(k14,k15)
    uint32_t Z0 = cvtpk_bf16(p[8],  p[9]);
    uint32_t Z1 = cvtpk_bf16(p[10], p[11]);
    uint32_t W0 = cvtpk_bf16(p[12], p[13]);
    uint32_t W1 = cvtpk_bf16(p[14], p[15]);
    uint32_t sZ0 = __shfl_xor(Z0, 32), sZ1 = __shfl_xor(Z1, 32);
    uint32_t sW0 = __shfl_xor(W0, 32), sW1 = __shfl_xor(W1, 32);
    uint4 f1;
    f1.x = h ? sW0 : Z0;   // h0:(k16,k17) h1:(k24,k25)
    f1.y = h ? sW1 : Z1;
    f1.z = h ? W0  : sZ0;
    f1.w = h ? W1  : sZ1;
    short8 pF0 = __builtin_bit_cast(short8, f0);   // keys kb+0..15
    short8 pF1 = __builtin_bit_cast(short8, f1);   // keys kb+16..31

    // ---- PV: O^T[n][q] += V^T-chunk x P ; A=Vt from LDS (lane-linear reads)
    __builtin_amdgcn_s_setprio(1);
#pragma unroll
    for (int nb = 0; nb < 8; ++nb){
      short8 v0 = *(const short8*)&ldsV[(nb * 2 + 0) * 512 + lane * 8];
      short8 v1 = *(const short8*)&ldsV[(nb * 2 + 1) * 512 + lane * 8];
      acc[nb] = __builtin_amdgcn_mfma_f32_32x32x16_bf16(v0, pF0, acc[nb], 0, 0, 0);
      acc[nb] = __builtin_amdgcn_mfma_f32_32x32x16_bf16(v1, pF1, acc[nb], 0, 0, 0);
    }
    __builtin_amdgcn_s_setprio(0);

    asm volatile("s_waitcnt vmcnt(0)" ::: "memory");
    __syncthreads();
    buf ^= 1;
  }

  // epilogue: lane owns query q31; n = nb*32 + rq*8 + h*4 + (r&3)
  lsum += __shfl_xor(lsum, 32);
  float r = 1.0f / lsum;
  float* op = Out + (long)head * T * D + (long)(qb + q31) * D + h * 4;
#pragma unroll
  for (int nb = 0; nb < 8; ++nb){
#pragma unroll
    for (int rq = 0; rq < 4; ++rq){
      f32x4 o;
      o.x = acc[nb][rq * 4 + 0] * r;
      o.y = acc[nb][rq * 4 + 1] * r;
      o.z = acc[nb][rq * 4 + 2] * r;
      o.w = acc[nb][rq * 4 + 3] * r;
      *(f32x4*)(op + nb * 32 + rq * 8) = o;
    }
  }
}

extern "C" void kernel_launch(void* const* d_in, const int* in_sizes, int n_in,
                              void* d_out, int out_size, void* d_ws, size_t ws_size,
                              hipStream_t stream){
  (void)in_sizes; (void)n_in; (void)out_size; (void)ws_size;
  const float* Q     = (const float*)d_in[0];
  const float* V     = (const float*)d_in[1];
  const float* freqs = (const float*)d_in[2];
  float* Out = (float*)d_out;
  unsigned short* QR = (unsigned short*)d_ws;                  // [96][1024][256] bf16
  unsigned short* Vt = QR + (size_t)BH * T * D;                // [96][256][1024] bf16
  k_rope<<<dim3((BH * T * D) / 4 / 256), dim3(256), 0, stream>>>(Q, freqs, QR);
  k_transpose<<<dim3(BH * 64), dim3(256), 0, stream>>>(V, Vt);
  k_flash<<<dim3(BH * 8), dim3(256), 0, stream>>>(QR, Vt, Out);
}